// Round 7
// baseline (167.549 us; speedup 1.0000x reference)
//
#include <hip/hip_runtime.h>
#include <hip/hip_bf16.h>
#include <stdint.h>

#define OUTN 4096
#define INN  4096
#define SPECN 512
#define BK 128
#define KSPLIT 2
#define KPB (OUTN / KSPLIT)   // 2048 k per block
#define TPB (KPB / BK)        // 16 tiles per block

typedef __attribute__((ext_vector_type(8))) short short8;
typedef __attribute__((ext_vector_type(4))) float f32x4;

__device__ __forceinline__ ushort f2bf(float f) {
    uint32_t u = __float_as_uint(f);
    uint32_t r = (u + 0x7FFFu + ((u >> 16) & 1u)) >> 16;
    return (ushort)r;
}
__device__ __forceinline__ float bf2f(ushort u) {
    return __uint_as_float((uint32_t)u << 16);
}

// ---------------------------------------------------------------------------
// prep: blocks [0,512) build A1/A2 (bf16) + ubias + rowmask.
// Blocks [512, 4608) transpose+convert W (f32 [o][i]) -> WT (bf16 [i][o]).
// (unchanged — near its BW floor)
// ---------------------------------------------------------------------------
__global__ __launch_bounds__(256) void prep(
    const float* __restrict__ uA, const float* __restrict__ W,
    const float* __restrict__ Bias, const float* __restrict__ Lb,
    const float* __restrict__ Ub, const float* __restrict__ Alpha,
    ushort* __restrict__ A1, ushort* __restrict__ A2, ushort* __restrict__ WT,
    unsigned long long* __restrict__ rowmask, float* __restrict__ ubias_out)
{
    const int tid = threadIdx.x;
    if (blockIdx.x < 512) {
        const int s = blockIdx.x;
        float acc = 0.f;
        unsigned long long msk = 0;
        for (int p = 0; p < 4; ++p) {
            const int o = p * 1024 + tid * 4;
            const float4 u4 = *(const float4*)&uA[(size_t)s * OUTN + o];
            const float4 lb4 = *(const float4*)&Lb[o];
            const float4 ub4 = *(const float4*)&Ub[o];
            const float4 b4 = *(const float4*)&Bias[o];
            const float4 a4 = *(const float4*)&Alpha[o];
            const float uu[4] = {u4.x, u4.y, u4.z, u4.w};
            const float lbv[4] = {lb4.x, lb4.y, lb4.z, lb4.w};
            const float ubv[4] = {ub4.x, ub4.y, ub4.z, ub4.w};
            const float bv[4] = {b4.x, b4.y, b4.z, b4.w};
            const float av[4] = {a4.x, a4.y, a4.z, a4.w};
            ushort r1[4], r2[4];
#pragma unroll
            for (int j = 0; j < 4; ++j) {
                const float u = uu[j], lb = lbv[j], ub = ubv[j], b = bv[j], a = av[j];
                const float pp = fmaxf(u, 0.f), nn = fminf(u, 0.f);
                const bool stneg = (ub <= 0.f);
                const bool stpos = (lb >= 0.f);
                const float lower_d = (fabsf(lb) >= fabsf(ub)) ? 1.f : 0.f;
                float lbr = fminf(lb, 0.f);
                float ubr = fmaxf(ub, 0.f);
                ubr = fmaxf(ubr, lbr + 1e-8f);
                const float ud = ubr / (ubr - lbr);
                const float upb = -lbr * ud;
                const float ldc = (ud > 0.5f) ? 1.f : 0.f;
                const float oma = 1.f - a;
                const float crown = ud * pp + ldc * nn;
                const float wcoef = a * crown +
                    oma * (stneg ? 0.f : (stpos ? (pp + nn) : lower_d * nn));
                const float scoef = (stneg || stpos) ? 0.f : oma * pp;
                const float ub_t = stneg ? 0.f : (stpos ? b : fmaxf(b, 0.f));
                const float lb_t = stneg ? 0.f : (stpos ? b : lower_d * b);
                acc += pp * (oma * ub_t + upb) + nn * (oma * lb_t) + crown * (a * b);
                r1[j] = f2bf(wcoef);
                r2[j] = f2bf(scoef);
            }
            *(ushort4*)&A1[(size_t)s * OUTN + o] = make_ushort4(r1[0], r1[1], r1[2], r1[3]);
            *(ushort4*)&A2[(size_t)s * OUTN + o] = make_ushort4(r2[0], r2[1], r2[2], r2[3]);
            if (((r2[0] | r2[1] | r2[2] | r2[3]) & 0x7FFF) != 0)
                msk |= 1ull << (p * 16 + (tid >> 4));
        }
#pragma unroll
        for (int off = 32; off; off >>= 1) {
            acc += __shfl_down(acc, off);
            msk |= __shfl_down(msk, off);
        }
        __shared__ float redf[4];
        __shared__ unsigned long long redm[4];
        if ((tid & 63) == 0) { redf[tid >> 6] = acc; redm[tid >> 6] = msk; }
        __syncthreads();
        if (tid == 0) {
            ubias_out[s] = redf[0] + redf[1] + redf[2] + redf[3];
            rowmask[s] = redm[0] | redm[1] | redm[2] | redm[3];
        }
    } else {
        __shared__ float t[64][65];
        const int tb = blockIdx.x - 512;
        const int bi = tb & 63, bo = tb >> 6;
        const int i0 = bi * 64, o0 = bo * 64;
        const int sub = tid >> 4;
        const int q4 = (tid & 15) * 4;
#pragma unroll
        for (int p = 0; p < 4; ++p) {
            const int ol = p * 16 + sub;
            const float4 w = *(const float4*)&W[(size_t)(o0 + ol) * INN + i0 + q4];
            t[q4 + 0][ol] = w.x;
            t[q4 + 1][ol] = w.y;
            t[q4 + 2][ol] = w.z;
            t[q4 + 3][ol] = w.w;
        }
        __syncthreads();
#pragma unroll
        for (int p = 0; p < 4; ++p) {
            const int il = p * 16 + sub;
            *(ushort4*)&WT[(size_t)(i0 + il) * OUTN + o0 + q4] =
                make_ushort4(f2bf(t[il][q4]), f2bf(t[il][q4 + 1]),
                             f2bf(t[il][q4 + 2]), f2bf(t[il][q4 + 3]));
        }
    }
}

// ---------------------------------------------------------------------------
// gemm (split-K): grid 1024 = 64 i-tiles x 8 s-tiles x KSPLIT. Block tile
// 64x64 over K=2048; BK=128; wave w computes the FULL 64x64 over its private
// k=32 slice (4x4 frags). B (WT) staged in LDS (2buf x 16KB, source-swizzled
// global_load_lds w16); A (A1) frags loaded straight from global to regs
// (rows are k-contiguous = native MFMA A layout). 4 blocks/CU -> 4 waves/SIMD.
// Wave accs tree-summed through the 32KB staging LDS; partial -> P[ks].
// ---------------------------------------------------------------------------
__global__ __launch_bounds__(256, 4) void gemm(
    const ushort* __restrict__ A1, const ushort* __restrict__ A2,
    const ushort* __restrict__ WT, const float* __restrict__ Bias,
    const unsigned long long* __restrict__ rowmask, float* __restrict__ P)
{
    __shared__ __align__(16) ushort sB[2][64 * BK];   // 32 KB

    // XCD-chunked: consecutive gid within an XCD share WT i-panels.
    const int bid = blockIdx.x;
    const int gid = (bid & 7) * 128 + (bid >> 3);
    const int bx = gid >> 4;          // i tile 0..63
    const int by = (gid >> 1) & 7;    // s tile 0..7
    const int ks = gid & 1;           // k split 0..1
    const int i0 = bx * 64, s0 = by * 64;
    const int k0 = ks * KPB;
    const int tid = threadIdx.x;
    const int lane = tid & 63;
    const int w = tid >> 6;

    unsigned long long smask = rowmask[s0 + lane];
#pragma unroll
    for (int off = 32; off; off >>= 1) smask |= __shfl_xor(smask, off);

    f32x4 acc[4][4] = {};

    // B staging: 16KB tile = 16 chunks of 1KB; wave w owns chunks w*4..w*4+3.
    // chunk c covers rows c*4..c*4+3 (256B rows); lane l -> row c*4+(l>>4),
    // slot l&15 holds global 16B k-chunk ((l&15) ^ (row&15)).
    auto stage = [&](int buf, int t) {
        const int ko = k0 + t * BK;
#pragma unroll
        for (int h = 0; h < 4; ++h) {
            const int c = w * 4 + h;
            const int row = c * 4 + (lane >> 4);
            const int g = (lane & 15) ^ (row & 15);
            __builtin_amdgcn_global_load_lds(
                (const __attribute__((address_space(1))) void*)(WT + (size_t)(i0 + row) * OUTN + ko + g * 8),
                (__attribute__((address_space(3))) void*)&sB[buf][c * 512], 16, 0, 0);
        }
    };

    // wave w consumes k-slice [w*32, w*32+32) of the staged tile; A from global.
    auto compute = [&](int buf, int t) {
        const int arow = lane & 15;
        const int kb = k0 + t * BK + w * 32 + (lane >> 4) * 8;
        short8 av[4], bv[4];
#pragma unroll
        for (int m = 0; m < 4; ++m)
            av[m] = *(const short8*)&A1[(size_t)(s0 + m * 16 + arow) * OUTN + kb];
        const int kc = w * 4 + (lane >> 4);
#pragma unroll
        for (int n = 0; n < 4; ++n) {
            const int r = n * 16 + arow;
            bv[n] = *(const short8*)&sB[buf][r * BK + (kc ^ (r & 15)) * 8];
        }
#pragma unroll
        for (int m = 0; m < 4; ++m)
#pragma unroll
            for (int n = 0; n < 4; ++n)
                acc[m][n] = __builtin_amdgcn_mfma_f32_16x16x32_bf16(
                    av[m], bv[n], acc[m][n], 0, 0, 0);
    };

    stage(0, 0);
    __syncthreads();
    for (int t = 0; t < TPB; ++t) {
        if (t + 1 < TPB) stage((t + 1) & 1, t + 1);   // prefetch under MFMA
        compute(t & 1, t);
        if (t + 1 < TPB) __syncthreads();
    }

    // rare path: simplex contribution for flagged 64-wide k-blocks inside this
    // split's K range. Pure global->reg, no LDS, no barriers (smask uniform).
    if (smask) {
        for (int b = ks * 32; b < ks * 32 + 32; ++b) {
            if (!((smask >> b) & 1)) continue;
            if (w < 2) {
                const int kk = w * 32;
                const int arow = lane & 15;
                const int kbb = b * 64 + kk + (lane >> 4) * 8;
                short8 av2[4], bw[4];
#pragma unroll
                for (int m = 0; m < 4; ++m)
                    av2[m] = *(const short8*)&A2[(size_t)(s0 + m * 16 + arow) * OUTN + kbb];
                const float4 b0 = *(const float4*)&Bias[kbb];
                const float4 b1 = *(const float4*)&Bias[kbb + 4];
                const float bb[8] = {b0.x, b0.y, b0.z, b0.w, b1.x, b1.y, b1.z, b1.w};
#pragma unroll
                for (int n = 0; n < 4; ++n) {
                    const short8 wv = *(const short8*)&WT[(size_t)(i0 + n * 16 + arow) * OUTN + kbb];
                    short8 sv;
#pragma unroll
                    for (int j = 0; j < 8; ++j) {
                        const float wf = bf2f((ushort)wv[j]);
                        sv[j] = (short)f2bf(fmaxf(wf + bb[j], 0.f) - fmaxf(bb[j], 0.f));
                    }
                    bw[n] = sv;
                }
#pragma unroll
                for (int m = 0; m < 4; ++m)
#pragma unroll
                    for (int n = 0; n < 4; ++n)
                        acc[m][n] = __builtin_amdgcn_mfma_f32_16x16x32_bf16(
                            av2[m], bw[n], acc[m][n], 0, 0, 0);
            }
        }
    }

    // epilogue: tree-sum 4 wave-accs via the 32KB staging LDS (2 rounds).
    __syncthreads();
    float* facc = (float*)&sB[0][0];   // 8192 floats
    if (w >= 2) {
#pragma unroll
        for (int m = 0; m < 4; ++m)
#pragma unroll
            for (int n = 0; n < 4; ++n)
                *(f32x4*)&facc[(w - 2) * 4096 + (m * 4 + n) * 256 + lane * 4] = acc[m][n];
    }
    __syncthreads();
    if (w < 2) {
#pragma unroll
        for (int m = 0; m < 4; ++m)
#pragma unroll
            for (int n = 0; n < 4; ++n) {
                const f32x4 v = *(const f32x4*)&facc[w * 4096 + (m * 4 + n) * 256 + lane * 4];
                acc[m][n] += v;
            }
    }
    __syncthreads();
    if (w == 0) {
#pragma unroll
        for (int m = 2; m < 4; ++m)
#pragma unroll
            for (int n = 0; n < 4; ++n)
                *(f32x4*)&facc[((m - 2) * 4 + n) * 256 + lane * 4] = acc[m][n];
    } else if (w == 1) {
#pragma unroll
        for (int m = 0; m < 2; ++m)
#pragma unroll
            for (int n = 0; n < 4; ++n)
                *(f32x4*)&facc[2048 + (m * 4 + n) * 256 + lane * 4] = acc[m][n];
    }
    __syncthreads();
    float* Pp = P + (size_t)ks * SPECN * INN;
    if (w == 0) {
#pragma unroll
        for (int m = 0; m < 2; ++m)
#pragma unroll
            for (int n = 0; n < 4; ++n) {
                const f32x4 v = *(const f32x4*)&facc[2048 + (m * 4 + n) * 256 + lane * 4];
                f32x4 s = acc[m][n]; s += v;
                const int srow = s0 + m * 16 + (lane >> 4) * 4;
                const int icol = i0 + n * 16 + (lane & 15);
#pragma unroll
                for (int r = 0; r < 4; ++r)
                    Pp[(size_t)(srow + r) * INN + icol] = s[r];
            }
    } else if (w == 1) {
#pragma unroll
        for (int m = 2; m < 4; ++m)
#pragma unroll
            for (int n = 0; n < 4; ++n) {
                const f32x4 v = *(const f32x4*)&facc[((m - 2) * 4 + n) * 256 + lane * 4];
                f32x4 s = acc[m][n]; s += v;
                const int srow = s0 + m * 16 + (lane >> 4) * 4;
                const int icol = i0 + n * 16 + (lane & 15);
#pragma unroll
                for (int r = 0; r < 4; ++r)
                    Pp[(size_t)(srow + r) * INN + icol] = s[r];
            }
    }
}

// ---------------------------------------------------------------------------
// reduce: out = P[0] + P[1] (split-K combine), vectorized.
// ---------------------------------------------------------------------------
__global__ __launch_bounds__(256) void reduce(
    const float* __restrict__ P, float* __restrict__ outp)
{
    const size_t idx = ((size_t)blockIdx.x * 256 + threadIdx.x) * 4;
    const f32x4 a = *(const f32x4*)&P[idx];
    const f32x4 b = *(const f32x4*)&P[(size_t)SPECN * INN + idx];
    f32x4 s = a; s += b;
    *(f32x4*)&outp[idx] = s;
}

// ---------------------------------------------------------------------------
extern "C" void kernel_launch(void* const* d_in, const int* in_sizes, int n_in,
                              void* d_out, int out_size, void* d_ws, size_t ws_size,
                              hipStream_t stream) {
    const float* uA    = (const float*)d_in[0];
    const float* W     = (const float*)d_in[1];
    const float* Bias  = (const float*)d_in[2];
    const float* Lb    = (const float*)d_in[3];
    const float* Ub    = (const float*)d_in[4];
    const float* Alpha = (const float*)d_in[5];
    float* outp = (float*)d_out;

    char* ws = (char*)d_ws;
    unsigned long long* rowmask = (unsigned long long*)ws;       // 4 KB
    ushort* A1 = (ushort*)(ws + 4096);                           // 4 MB
    ushort* A2 = (ushort*)(ws + 4096 + (1u << 22));              // 4 MB
    ushort* WT = (ushort*)(ws + 4096 + (2u << 22));              // 32 MB
    float*  P  = (float*)(ws + 4096 + (2u << 22) + (1u << 25));  // 16.8 MB

    prep<<<4608, 256, 0, stream>>>(uA, W, Bias, Lb, Ub, Alpha, A1, A2, WT,
                                   rowmask, outp + (size_t)SPECN * INN);
    gemm<<<1024, 256, 0, stream>>>(A1, A2, WT, Bias, rowmask, P);
    reduce<<<(SPECN * INN) / 1024, 256, 0, stream>>>(P, outp);
}

// Round 8
// 152.276 us; speedup vs baseline: 1.1003x; 1.1003x over previous
//
#include <hip/hip_runtime.h>
#include <hip/hip_bf16.h>
#include <stdint.h>

#define OUTN 4096
#define INN  4096
#define SPECN 512
#define BK 128
#define KSPLIT 2
#define KPB (OUTN / KSPLIT)   // 2048 k per block
#define TPB (KPB / BK)        // 16 tiles per block

typedef __attribute__((ext_vector_type(8))) short short8;
typedef __attribute__((ext_vector_type(4))) float f32x4;

__device__ __forceinline__ ushort f2bf(float f) {
    uint32_t u = __float_as_uint(f);
    uint32_t r = (u + 0x7FFFu + ((u >> 16) & 1u)) >> 16;
    return (ushort)r;
}
__device__ __forceinline__ float bf2f(ushort u) {
    return __uint_as_float((uint32_t)u << 16);
}

// ---------------------------------------------------------------------------
// prep: blocks [0,512) build Apack (A-coefficients in MFMA-fragment-packed
// order) + A2 (row-major, rare path) + ubias + rowmask.
// Blocks [512, 4608) transpose+convert W (f32 [o][i]) -> WT (bf16 [i][o]).
//
// Apack layout (ushort): [sb 0..7][k32 0..127][m 0..3][lane 0..63][j 0..7]
//   element (s, o):  sb=s>>6, m=(s>>4)&3, arow=s&15
//                    k32=o>>5, kslot=(o>>3)&3, j=o&7, lane=kslot*16+arow
// A wave's av[m] fragment = 1KB contiguous (lane-sequential, 16B/lane).
// ---------------------------------------------------------------------------
__global__ __launch_bounds__(256) void prep(
    const float* __restrict__ uA, const float* __restrict__ W,
    const float* __restrict__ Bias, const float* __restrict__ Lb,
    const float* __restrict__ Ub, const float* __restrict__ Alpha,
    ushort* __restrict__ Apack, ushort* __restrict__ A2, ushort* __restrict__ WT,
    unsigned long long* __restrict__ rowmask, float* __restrict__ ubias_out)
{
    const int tid = threadIdx.x;
    if (blockIdx.x < 512) {
        const int s = blockIdx.x;
        const int sb = s >> 6, m = (s >> 4) & 3, arow = s & 15;
        float acc = 0.f;
        unsigned long long msk = 0;
        for (int p = 0; p < 4; ++p) {
            const int o = p * 1024 + tid * 4;
            const float4 u4 = *(const float4*)&uA[(size_t)s * OUTN + o];
            const float4 lb4 = *(const float4*)&Lb[o];
            const float4 ub4 = *(const float4*)&Ub[o];
            const float4 b4 = *(const float4*)&Bias[o];
            const float4 a4 = *(const float4*)&Alpha[o];
            const float uu[4] = {u4.x, u4.y, u4.z, u4.w};
            const float lbv[4] = {lb4.x, lb4.y, lb4.z, lb4.w};
            const float ubv[4] = {ub4.x, ub4.y, ub4.z, ub4.w};
            const float bv[4] = {b4.x, b4.y, b4.z, b4.w};
            const float av[4] = {a4.x, a4.y, a4.z, a4.w};
            ushort r1[4], r2[4];
#pragma unroll
            for (int j = 0; j < 4; ++j) {
                const float u = uu[j], lb = lbv[j], ub = ubv[j], b = bv[j], a = av[j];
                const float pp = fmaxf(u, 0.f), nn = fminf(u, 0.f);
                const bool stneg = (ub <= 0.f);
                const bool stpos = (lb >= 0.f);
                const float lower_d = (fabsf(lb) >= fabsf(ub)) ? 1.f : 0.f;
                float lbr = fminf(lb, 0.f);
                float ubr = fmaxf(ub, 0.f);
                ubr = fmaxf(ubr, lbr + 1e-8f);
                const float ud = ubr / (ubr - lbr);
                const float upb = -lbr * ud;
                const float ldc = (ud > 0.5f) ? 1.f : 0.f;
                const float oma = 1.f - a;
                const float crown = ud * pp + ldc * nn;
                const float wcoef = a * crown +
                    oma * (stneg ? 0.f : (stpos ? (pp + nn) : lower_d * nn));
                const float scoef = (stneg || stpos) ? 0.f : oma * pp;
                const float ub_t = stneg ? 0.f : (stpos ? b : fmaxf(b, 0.f));
                const float lb_t = stneg ? 0.f : (stpos ? b : lower_d * b);
                acc += pp * (oma * ub_t + upb) + nn * (oma * lb_t) + crown * (a * b);
                r1[j] = f2bf(wcoef);
                r2[j] = f2bf(scoef);
            }
            // fragment-packed store of the 4 weight-coefficients
            const int k32 = o >> 5;
            const int kslot = (o >> 3) & 3;
            const int jj = o & 7;
            const size_t pi = (((size_t)sb * 128 + k32) * 4 + m) * 512 +
                              (kslot * 16 + arow) * 8 + jj;
            *(ushort4*)&Apack[pi] = make_ushort4(r1[0], r1[1], r1[2], r1[3]);
            *(ushort4*)&A2[(size_t)s * OUTN + o] = make_ushort4(r2[0], r2[1], r2[2], r2[3]);
            if (((r2[0] | r2[1] | r2[2] | r2[3]) & 0x7FFF) != 0)
                msk |= 1ull << (p * 16 + (tid >> 4));
        }
#pragma unroll
        for (int off = 32; off; off >>= 1) {
            acc += __shfl_down(acc, off);
            msk |= __shfl_down(msk, off);
        }
        __shared__ float redf[4];
        __shared__ unsigned long long redm[4];
        if ((tid & 63) == 0) { redf[tid >> 6] = acc; redm[tid >> 6] = msk; }
        __syncthreads();
        if (tid == 0) {
            ubias_out[s] = redf[0] + redf[1] + redf[2] + redf[3];
            rowmask[s] = redm[0] | redm[1] | redm[2] | redm[3];
        }
    } else {
        __shared__ float t[64][65];
        const int tb = blockIdx.x - 512;
        const int bi = tb & 63, bo = tb >> 6;
        const int i0 = bi * 64, o0 = bo * 64;
        const int sub = tid >> 4;
        const int q4 = (tid & 15) * 4;
#pragma unroll
        for (int p = 0; p < 4; ++p) {
            const int ol = p * 16 + sub;
            const float4 w = *(const float4*)&W[(size_t)(o0 + ol) * INN + i0 + q4];
            t[q4 + 0][ol] = w.x;
            t[q4 + 1][ol] = w.y;
            t[q4 + 2][ol] = w.z;
            t[q4 + 3][ol] = w.w;
        }
        __syncthreads();
#pragma unroll
        for (int p = 0; p < 4; ++p) {
            const int il = p * 16 + sub;
            *(ushort4*)&WT[(size_t)(i0 + il) * OUTN + o0 + q4] =
                make_ushort4(f2bf(t[il][q4]), f2bf(t[il][q4 + 1]),
                             f2bf(t[il][q4 + 2]), f2bf(t[il][q4 + 3]));
        }
    }
}

// ---------------------------------------------------------------------------
// gemm (split-K): grid 1024 = 64 i-tiles x 8 s-tiles x KSPLIT. Block tile
// 64x64 over K=2048; BK=128; wave w computes the FULL 64x64 (4x4 frags) over
// its private k=32 slice. B (WT) staged in LDS (2buf x 16KB, source-swizzled
// global_load_lds w16); A frags are single COALESCED 1KB wave-loads from
// Apack (fragment-packed by prep) straight to registers. 4 blocks/CU.
// Wave accs tree-summed through the 32KB staging LDS; partial -> P[ks].
// ---------------------------------------------------------------------------
__global__ __launch_bounds__(256, 4) void gemm(
    const ushort* __restrict__ Apack, const ushort* __restrict__ A2,
    const ushort* __restrict__ WT, const float* __restrict__ Bias,
    const unsigned long long* __restrict__ rowmask, float* __restrict__ P)
{
    __shared__ __align__(16) ushort sB[2][64 * BK];   // 32 KB

    // XCD-chunked: consecutive gid within an XCD share WT i-panels.
    const int bid = blockIdx.x;
    const int gid = (bid & 7) * 128 + (bid >> 3);
    const int bx = gid >> 4;          // i tile 0..63
    const int by = (gid >> 1) & 7;    // s tile 0..7
    const int ks = gid & 1;           // k split 0..1
    const int i0 = bx * 64, s0 = by * 64;
    const int k0 = ks * KPB;
    const int tid = threadIdx.x;
    const int lane = tid & 63;
    const int w = tid >> 6;

    unsigned long long smask = rowmask[s0 + lane];
#pragma unroll
    for (int off = 32; off; off >>= 1) smask |= __shfl_xor(smask, off);

    f32x4 acc[4][4] = {};

    // B staging: 16KB tile = 16 chunks of 1KB; wave w owns chunks w*4..w*4+3.
    auto stage = [&](int buf, int t) {
        const int ko = k0 + t * BK;
#pragma unroll
        for (int h = 0; h < 4; ++h) {
            const int c = w * 4 + h;
            const int row = c * 4 + (lane >> 4);
            const int g = (lane & 15) ^ (row & 15);
            __builtin_amdgcn_global_load_lds(
                (const __attribute__((address_space(1))) void*)(WT + (size_t)(i0 + row) * OUTN + ko + g * 8),
                (__attribute__((address_space(3))) void*)&sB[buf][c * 512], 16, 0, 0);
        }
    };

    // wave w consumes k-slice [w*32, w*32+32); A frags coalesced from Apack.
    auto compute = [&](int buf, int t) {
        const int k32w = ks * 64 + t * 4 + w;
        const size_t abase = (((size_t)by * 128 + k32w) * 4) * 512 + lane * 8;
        short8 av[4], bv[4];
#pragma unroll
        for (int m = 0; m < 4; ++m)
            av[m] = *(const short8*)&Apack[abase + m * 512];
        const int kc = w * 4 + (lane >> 4);
#pragma unroll
        for (int n = 0; n < 4; ++n) {
            const int r = n * 16 + (lane & 15);
            bv[n] = *(const short8*)&sB[buf][r * BK + (kc ^ (r & 15)) * 8];
        }
#pragma unroll
        for (int m = 0; m < 4; ++m)
#pragma unroll
            for (int n = 0; n < 4; ++n)
                acc[m][n] = __builtin_amdgcn_mfma_f32_16x16x32_bf16(
                    av[m], bv[n], acc[m][n], 0, 0, 0);
    };

    stage(0, 0);
    __syncthreads();
    for (int t = 0; t < TPB; ++t) {
        if (t + 1 < TPB) stage((t + 1) & 1, t + 1);   // prefetch under MFMA
        compute(t & 1, t);
        if (t + 1 < TPB) __syncthreads();
    }

    // rare path: simplex contribution for flagged 64-wide k-blocks inside this
    // split's K range. Pure global->reg, no LDS, no barriers (smask uniform).
    if (smask) {
        for (int b = ks * 32; b < ks * 32 + 32; ++b) {
            if (!((smask >> b) & 1)) continue;
            if (w < 2) {
                const int kk = w * 32;
                const int arow = lane & 15;
                const int kbb = b * 64 + kk + (lane >> 4) * 8;
                short8 av2[4], bw[4];
#pragma unroll
                for (int m = 0; m < 4; ++m)
                    av2[m] = *(const short8*)&A2[(size_t)(s0 + m * 16 + arow) * OUTN + kbb];
                const float4 b0 = *(const float4*)&Bias[kbb];
                const float4 b1 = *(const float4*)&Bias[kbb + 4];
                const float bb[8] = {b0.x, b0.y, b0.z, b0.w, b1.x, b1.y, b1.z, b1.w};
#pragma unroll
                for (int n = 0; n < 4; ++n) {
                    const short8 wv = *(const short8*)&WT[(size_t)(i0 + n * 16 + arow) * OUTN + kbb];
                    short8 sv;
#pragma unroll
                    for (int j = 0; j < 8; ++j) {
                        const float wf = bf2f((ushort)wv[j]);
                        sv[j] = (short)f2bf(fmaxf(wf + bb[j], 0.f) - fmaxf(bb[j], 0.f));
                    }
                    bw[n] = sv;
                }
#pragma unroll
                for (int m = 0; m < 4; ++m)
#pragma unroll
                    for (int n = 0; n < 4; ++n)
                        acc[m][n] = __builtin_amdgcn_mfma_f32_16x16x32_bf16(
                            av2[m], bw[n], acc[m][n], 0, 0, 0);
            }
        }
    }

    // epilogue: tree-sum 4 wave-accs via the 32KB staging LDS (2 rounds).
    __syncthreads();
    float* facc = (float*)&sB[0][0];   // 8192 floats
    if (w >= 2) {
#pragma unroll
        for (int m = 0; m < 4; ++m)
#pragma unroll
            for (int n = 0; n < 4; ++n)
                *(f32x4*)&facc[(w - 2) * 4096 + (m * 4 + n) * 256 + lane * 4] = acc[m][n];
    }
    __syncthreads();
    if (w < 2) {
#pragma unroll
        for (int m = 0; m < 4; ++m)
#pragma unroll
            for (int n = 0; n < 4; ++n) {
                const f32x4 v = *(const f32x4*)&facc[w * 4096 + (m * 4 + n) * 256 + lane * 4];
                acc[m][n] += v;
            }
    }
    __syncthreads();
    if (w == 0) {
#pragma unroll
        for (int m = 2; m < 4; ++m)
#pragma unroll
            for (int n = 0; n < 4; ++n)
                *(f32x4*)&facc[((m - 2) * 4 + n) * 256 + lane * 4] = acc[m][n];
    } else if (w == 1) {
#pragma unroll
        for (int m = 0; m < 2; ++m)
#pragma unroll
            for (int n = 0; n < 4; ++n)
                *(f32x4*)&facc[2048 + (m * 4 + n) * 256 + lane * 4] = acc[m][n];
    }
    __syncthreads();
    float* Pp = P + (size_t)ks * SPECN * INN;
    if (w == 0) {
#pragma unroll
        for (int m = 0; m < 2; ++m)
#pragma unroll
            for (int n = 0; n < 4; ++n) {
                const f32x4 v = *(const f32x4*)&facc[2048 + (m * 4 + n) * 256 + lane * 4];
                f32x4 s = acc[m][n]; s += v;
                const int srow = s0 + m * 16 + (lane >> 4) * 4;
                const int icol = i0 + n * 16 + (lane & 15);
#pragma unroll
                for (int r = 0; r < 4; ++r)
                    Pp[(size_t)(srow + r) * INN + icol] = s[r];
            }
    } else if (w == 1) {
#pragma unroll
        for (int m = 2; m < 4; ++m)
#pragma unroll
            for (int n = 0; n < 4; ++n) {
                const f32x4 v = *(const f32x4*)&facc[((m - 2) * 4 + n) * 256 + lane * 4];
                f32x4 s = acc[m][n]; s += v;
                const int srow = s0 + m * 16 + (lane >> 4) * 4;
                const int icol = i0 + n * 16 + (lane & 15);
#pragma unroll
                for (int r = 0; r < 4; ++r)
                    Pp[(size_t)(srow + r) * INN + icol] = s[r];
            }
    }
}

// ---------------------------------------------------------------------------
// reduce: out = P[0] + P[1] (split-K combine), vectorized.
// ---------------------------------------------------------------------------
__global__ __launch_bounds__(256) void reduce(
    const float* __restrict__ P, float* __restrict__ outp)
{
    const size_t idx = ((size_t)blockIdx.x * 256 + threadIdx.x) * 4;
    const f32x4 a = *(const f32x4*)&P[idx];
    const f32x4 b = *(const f32x4*)&P[(size_t)SPECN * INN + idx];
    f32x4 s = a; s += b;
    *(f32x4*)&outp[idx] = s;
}

// ---------------------------------------------------------------------------
extern "C" void kernel_launch(void* const* d_in, const int* in_sizes, int n_in,
                              void* d_out, int out_size, void* d_ws, size_t ws_size,
                              hipStream_t stream) {
    const float* uA    = (const float*)d_in[0];
    const float* W     = (const float*)d_in[1];
    const float* Bias  = (const float*)d_in[2];
    const float* Lb    = (const float*)d_in[3];
    const float* Ub    = (const float*)d_in[4];
    const float* Alpha = (const float*)d_in[5];
    float* outp = (float*)d_out;

    char* ws = (char*)d_ws;
    unsigned long long* rowmask = (unsigned long long*)ws;       // 4 KB
    ushort* Apack = (ushort*)(ws + 4096);                        // 4 MB
    ushort* A2 = (ushort*)(ws + 4096 + (1u << 22));              // 4 MB
    ushort* WT = (ushort*)(ws + 4096 + (2u << 22));              // 32 MB
    float*  P  = (float*)(ws + 4096 + (2u << 22) + (1u << 25));  // 16.8 MB

    prep<<<4608, 256, 0, stream>>>(uA, W, Bias, Lb, Ub, Alpha, Apack, A2, WT,
                                   rowmask, outp + (size_t)SPECN * INN);
    gemm<<<1024, 256, 0, stream>>>(Apack, A2, WT, Bias, rowmask, P);
    reduce<<<(SPECN * INN) / 1024, 256, 0, stream>>>(P, outp);
}

// Round 9
// 146.733 us; speedup vs baseline: 1.1419x; 1.0378x over previous
//
#include <hip/hip_runtime.h>
#include <hip/hip_bf16.h>
#include <stdint.h>

#define OUTN 4096
#define INN  4096
#define SPECN 512
#define BK 128
#define KSPLIT 2
#define KPB (OUTN / KSPLIT)   // 2048 k per block
#define TPB (KPB / BK)        // 16 tiles per block

typedef __attribute__((ext_vector_type(8))) short short8;
typedef __attribute__((ext_vector_type(4))) float f32x4;

__device__ __forceinline__ ushort f2bf(float f) {
    uint32_t u = __float_as_uint(f);
    uint32_t r = (u + 0x7FFFu + ((u >> 16) & 1u)) >> 16;
    return (ushort)r;
}
__device__ __forceinline__ float bf2f(ushort u) {
    return __uint_as_float((uint32_t)u << 16);
}

// ---------------------------------------------------------------------------
// prep: blocks [0,512) build Apack (MFMA-fragment-packed A) + A2 + ubias +
// rowmask — all global stores 16B. Blocks [512, 4608) transpose W -> WT with
// 16B stores (stage-2 reads 8 scalars/thread, conflict-free bank pattern).
//
// Apack layout (ushort): [sb 0..7][k32 0..127][m 0..3][lane 0..63][j 0..7]
//   element (s, o):  sb=s>>6, m=(s>>4)&3, arow=s&15
//                    k32=o>>5, kslot=(o>>3)&3, j=o&7, lane=kslot*16+arow
// ---------------------------------------------------------------------------
__global__ __launch_bounds__(256) void prep(
    const float* __restrict__ uA, const float* __restrict__ W,
    const float* __restrict__ Bias, const float* __restrict__ Lb,
    const float* __restrict__ Ub, const float* __restrict__ Alpha,
    ushort* __restrict__ Apack, ushort* __restrict__ A2, ushort* __restrict__ WT,
    unsigned long long* __restrict__ rowmask, float* __restrict__ ubias_out)
{
    const int tid = threadIdx.x;
    if (blockIdx.x < 512) {
        const int s = blockIdx.x;
        const int sb = s >> 6, m = (s >> 4) & 3, arow = s & 15;
        float acc = 0.f;
        unsigned long long msk = 0;
#pragma unroll
        for (int p = 0; p < 2; ++p) {
            const int o = p * 2048 + tid * 8;
            const size_t so = (size_t)s * OUTN + o;
            const float4 u40 = *(const float4*)&uA[so];
            const float4 u41 = *(const float4*)&uA[so + 4];
            const float4 lb0 = *(const float4*)&Lb[o];
            const float4 lb1 = *(const float4*)&Lb[o + 4];
            const float4 ub0 = *(const float4*)&Ub[o];
            const float4 ub1 = *(const float4*)&Ub[o + 4];
            const float4 b40 = *(const float4*)&Bias[o];
            const float4 b41 = *(const float4*)&Bias[o + 4];
            const float4 a40 = *(const float4*)&Alpha[o];
            const float4 a41 = *(const float4*)&Alpha[o + 4];
            const float uu[8]  = {u40.x, u40.y, u40.z, u40.w, u41.x, u41.y, u41.z, u41.w};
            const float lbv[8] = {lb0.x, lb0.y, lb0.z, lb0.w, lb1.x, lb1.y, lb1.z, lb1.w};
            const float ubv[8] = {ub0.x, ub0.y, ub0.z, ub0.w, ub1.x, ub1.y, ub1.z, ub1.w};
            const float bv[8]  = {b40.x, b40.y, b40.z, b40.w, b41.x, b41.y, b41.z, b41.w};
            const float av[8]  = {a40.x, a40.y, a40.z, a40.w, a41.x, a41.y, a41.z, a41.w};
            short8 s1, s2;
            int nz = 0;
#pragma unroll
            for (int j = 0; j < 8; ++j) {
                const float u = uu[j], lb = lbv[j], ub = ubv[j], b = bv[j], a = av[j];
                const float pp = fmaxf(u, 0.f), nn = fminf(u, 0.f);
                const bool stneg = (ub <= 0.f);
                const bool stpos = (lb >= 0.f);
                const float lower_d = (fabsf(lb) >= fabsf(ub)) ? 1.f : 0.f;
                float lbr = fminf(lb, 0.f);
                float ubr = fmaxf(ub, 0.f);
                ubr = fmaxf(ubr, lbr + 1e-8f);
                const float ud = ubr / (ubr - lbr);
                const float upb = -lbr * ud;
                const float ldc = (ud > 0.5f) ? 1.f : 0.f;
                const float oma = 1.f - a;
                const float crown = ud * pp + ldc * nn;
                const float wcoef = a * crown +
                    oma * (stneg ? 0.f : (stpos ? (pp + nn) : lower_d * nn));
                const float scoef = (stneg || stpos) ? 0.f : oma * pp;
                const float ub_t = stneg ? 0.f : (stpos ? b : fmaxf(b, 0.f));
                const float lb_t = stneg ? 0.f : (stpos ? b : lower_d * b);
                acc += pp * (oma * ub_t + upb) + nn * (oma * lb_t) + crown * (a * b);
                const ushort w1 = f2bf(wcoef), w2 = f2bf(scoef);
                s1[j] = (short)w1;
                s2[j] = (short)w2;
                nz |= (w2 & 0x7FFF);
            }
            // fragment-packed 16B store (o octet-aligned: jj=0, kslot const)
            const int k32 = o >> 5;
            const int kslot = (o >> 3) & 3;
            const size_t pi = (((size_t)sb * 128 + k32) * 4 + m) * 512 +
                              (kslot * 16 + arow) * 8;
            *(short8*)&Apack[pi] = s1;
            *(short8*)&A2[so] = s2;
            if (nz) msk |= 1ull << (p * 32 + (tid >> 3));
        }
#pragma unroll
        for (int off = 32; off; off >>= 1) {
            acc += __shfl_down(acc, off);
            msk |= __shfl_down(msk, off);
        }
        __shared__ float redf[4];
        __shared__ unsigned long long redm[4];
        if ((tid & 63) == 0) { redf[tid >> 6] = acc; redm[tid >> 6] = msk; }
        __syncthreads();
        if (tid == 0) {
            ubias_out[s] = redf[0] + redf[1] + redf[2] + redf[3];
            rowmask[s] = redm[0] | redm[1] | redm[2] | redm[3];
        }
    } else {
        __shared__ float t[64][65];
        const int tb = blockIdx.x - 512;
        const int bi = tb & 63, bo = tb >> 6;
        const int i0 = bi * 64, o0 = bo * 64;
        const int sub = tid >> 4;        // 0..15
        const int q4 = (tid & 15) * 4;   // 0..60
#pragma unroll
        for (int p = 0; p < 4; ++p) {
            const int ol = p * 16 + sub;
            const float4 w = *(const float4*)&W[(size_t)(o0 + ol) * INN + i0 + q4];
            t[q4 + 0][ol] = w.x;
            t[q4 + 1][ol] = w.y;
            t[q4 + 2][ol] = w.z;
            t[q4 + 3][ol] = w.w;
        }
        __syncthreads();
        // stage 2: one 16B store per thread per pass; LDS reads 2-way (free).
#pragma unroll
        for (int pp = 0; pp < 2; ++pp) {
            const int il = pp * 32 + (tid >> 3);   // 0..63
            const int q8 = (tid & 7) * 8;          // 0..56
            short8 outv;
#pragma unroll
            for (int j = 0; j < 8; ++j)
                outv[j] = (short)f2bf(t[il][q8 + j]);
            *(short8*)&WT[(size_t)(i0 + il) * OUTN + o0 + q8] = outv;
        }
    }
}

// ---------------------------------------------------------------------------
// gemm (split-K) — BYTE-IDENTICAL to round 8 (passing, ~25-30us).
// ---------------------------------------------------------------------------
__global__ __launch_bounds__(256, 4) void gemm(
    const ushort* __restrict__ Apack, const ushort* __restrict__ A2,
    const ushort* __restrict__ WT, const float* __restrict__ Bias,
    const unsigned long long* __restrict__ rowmask, float* __restrict__ P)
{
    __shared__ __align__(16) ushort sB[2][64 * BK];   // 32 KB

    const int bid = blockIdx.x;
    const int gid = (bid & 7) * 128 + (bid >> 3);
    const int bx = gid >> 4;          // i tile 0..63
    const int by = (gid >> 1) & 7;    // s tile 0..7
    const int ks = gid & 1;           // k split 0..1
    const int i0 = bx * 64, s0 = by * 64;
    const int k0 = ks * KPB;
    const int tid = threadIdx.x;
    const int lane = tid & 63;
    const int w = tid >> 6;

    unsigned long long smask = rowmask[s0 + lane];
#pragma unroll
    for (int off = 32; off; off >>= 1) smask |= __shfl_xor(smask, off);

    f32x4 acc[4][4] = {};

    auto stage = [&](int buf, int t) {
        const int ko = k0 + t * BK;
#pragma unroll
        for (int h = 0; h < 4; ++h) {
            const int c = w * 4 + h;
            const int row = c * 4 + (lane >> 4);
            const int g = (lane & 15) ^ (row & 15);
            __builtin_amdgcn_global_load_lds(
                (const __attribute__((address_space(1))) void*)(WT + (size_t)(i0 + row) * OUTN + ko + g * 8),
                (__attribute__((address_space(3))) void*)&sB[buf][c * 512], 16, 0, 0);
        }
    };

    auto compute = [&](int buf, int t) {
        const int k32w = ks * 64 + t * 4 + w;
        const size_t abase = (((size_t)by * 128 + k32w) * 4) * 512 + lane * 8;
        short8 av[4], bv[4];
#pragma unroll
        for (int m = 0; m < 4; ++m)
            av[m] = *(const short8*)&Apack[abase + m * 512];
        const int kc = w * 4 + (lane >> 4);
#pragma unroll
        for (int n = 0; n < 4; ++n) {
            const int r = n * 16 + (lane & 15);
            bv[n] = *(const short8*)&sB[buf][r * BK + (kc ^ (r & 15)) * 8];
        }
#pragma unroll
        for (int m = 0; m < 4; ++m)
#pragma unroll
            for (int n = 0; n < 4; ++n)
                acc[m][n] = __builtin_amdgcn_mfma_f32_16x16x32_bf16(
                    av[m], bv[n], acc[m][n], 0, 0, 0);
    };

    stage(0, 0);
    __syncthreads();
    for (int t = 0; t < TPB; ++t) {
        if (t + 1 < TPB) stage((t + 1) & 1, t + 1);
        compute(t & 1, t);
        if (t + 1 < TPB) __syncthreads();
    }

    if (smask) {
        for (int b = ks * 32; b < ks * 32 + 32; ++b) {
            if (!((smask >> b) & 1)) continue;
            if (w < 2) {
                const int kk = w * 32;
                const int arow = lane & 15;
                const int kbb = b * 64 + kk + (lane >> 4) * 8;
                short8 av2[4], bw[4];
#pragma unroll
                for (int m = 0; m < 4; ++m)
                    av2[m] = *(const short8*)&A2[(size_t)(s0 + m * 16 + arow) * OUTN + kbb];
                const float4 b0 = *(const float4*)&Bias[kbb];
                const float4 b1 = *(const float4*)&Bias[kbb + 4];
                const float bb[8] = {b0.x, b0.y, b0.z, b0.w, b1.x, b1.y, b1.z, b1.w};
#pragma unroll
                for (int n = 0; n < 4; ++n) {
                    const short8 wv = *(const short8*)&WT[(size_t)(i0 + n * 16 + arow) * OUTN + kbb];
                    short8 sv;
#pragma unroll
                    for (int j = 0; j < 8; ++j) {
                        const float wf = bf2f((ushort)wv[j]);
                        sv[j] = (short)f2bf(fmaxf(wf + bb[j], 0.f) - fmaxf(bb[j], 0.f));
                    }
                    bw[n] = sv;
                }
#pragma unroll
                for (int m = 0; m < 4; ++m)
#pragma unroll
                    for (int n = 0; n < 4; ++n)
                        acc[m][n] = __builtin_amdgcn_mfma_f32_16x16x32_bf16(
                            av2[m], bw[n], acc[m][n], 0, 0, 0);
            }
        }
    }

    __syncthreads();
    float* facc = (float*)&sB[0][0];
    if (w >= 2) {
#pragma unroll
        for (int m = 0; m < 4; ++m)
#pragma unroll
            for (int n = 0; n < 4; ++n)
                *(f32x4*)&facc[(w - 2) * 4096 + (m * 4 + n) * 256 + lane * 4] = acc[m][n];
    }
    __syncthreads();
    if (w < 2) {
#pragma unroll
        for (int m = 0; m < 4; ++m)
#pragma unroll
            for (int n = 0; n < 4; ++n) {
                const f32x4 v = *(const f32x4*)&facc[w * 4096 + (m * 4 + n) * 256 + lane * 4];
                acc[m][n] += v;
            }
    }
    __syncthreads();
    if (w == 0) {
#pragma unroll
        for (int m = 2; m < 4; ++m)
#pragma unroll
            for (int n = 0; n < 4; ++n)
                *(f32x4*)&facc[((m - 2) * 4 + n) * 256 + lane * 4] = acc[m][n];
    } else if (w == 1) {
#pragma unroll
        for (int m = 0; m < 2; ++m)
#pragma unroll
            for (int n = 0; n < 4; ++n)
                *(f32x4*)&facc[2048 + (m * 4 + n) * 256 + lane * 4] = acc[m][n];
    }
    __syncthreads();
    float* Pp = P + (size_t)ks * SPECN * INN;
    if (w == 0) {
#pragma unroll
        for (int m = 0; m < 2; ++m)
#pragma unroll
            for (int n = 0; n < 4; ++n) {
                const f32x4 v = *(const f32x4*)&facc[2048 + (m * 4 + n) * 256 + lane * 4];
                f32x4 s = acc[m][n]; s += v;
                const int srow = s0 + m * 16 + (lane >> 4) * 4;
                const int icol = i0 + n * 16 + (lane & 15);
#pragma unroll
                for (int r = 0; r < 4; ++r)
                    Pp[(size_t)(srow + r) * INN + icol] = s[r];
            }
    } else if (w == 1) {
#pragma unroll
        for (int m = 2; m < 4; ++m)
#pragma unroll
            for (int n = 0; n < 4; ++n) {
                const f32x4 v = *(const f32x4*)&facc[((m - 2) * 4 + n) * 256 + lane * 4];
                f32x4 s = acc[m][n]; s += v;
                const int srow = s0 + m * 16 + (lane >> 4) * 4;
                const int icol = i0 + n * 16 + (lane & 15);
#pragma unroll
                for (int r = 0; r < 4; ++r)
                    Pp[(size_t)(srow + r) * INN + icol] = s[r];
            }
    }
}

// ---------------------------------------------------------------------------
// reduce: out = P[0] + P[1] (split-K combine), vectorized.
// ---------------------------------------------------------------------------
__global__ __launch_bounds__(256) void reduce(
    const float* __restrict__ P, float* __restrict__ outp)
{
    const size_t idx = ((size_t)blockIdx.x * 256 + threadIdx.x) * 4;
    const f32x4 a = *(const f32x4*)&P[idx];
    const f32x4 b = *(const f32x4*)&P[(size_t)SPECN * INN + idx];
    f32x4 s = a; s += b;
    *(f32x4*)&outp[idx] = s;
}

// ---------------------------------------------------------------------------
extern "C" void kernel_launch(void* const* d_in, const int* in_sizes, int n_in,
                              void* d_out, int out_size, void* d_ws, size_t ws_size,
                              hipStream_t stream) {
    const float* uA    = (const float*)d_in[0];
    const float* W     = (const float*)d_in[1];
    const float* Bias  = (const float*)d_in[2];
    const float* Lb    = (const float*)d_in[3];
    const float* Ub    = (const float*)d_in[4];
    const float* Alpha = (const float*)d_in[5];
    float* outp = (float*)d_out;

    char* ws = (char*)d_ws;
    unsigned long long* rowmask = (unsigned long long*)ws;       // 4 KB
    ushort* Apack = (ushort*)(ws + 4096);                        // 4 MB
    ushort* A2 = (ushort*)(ws + 4096 + (1u << 22));              // 4 MB
    ushort* WT = (ushort*)(ws + 4096 + (2u << 22));              // 32 MB
    float*  P  = (float*)(ws + 4096 + (2u << 22) + (1u << 25));  // 16.8 MB

    prep<<<4608, 256, 0, stream>>>(uA, W, Bias, Lb, Ub, Alpha, Apack, A2, WT,
                                   rowmask, outp + (size_t)SPECN * INN);
    gemm<<<1024, 256, 0, stream>>>(Apack, A2, WT, Bias, rowmask, P);
    reduce<<<(SPECN * INN) / 1024, 256, 0, stream>>>(P, outp);
}